// Round 1
// baseline (680.350 us; speedup 1.0000x reference)
//
#include <hip/hip_runtime.h>

typedef unsigned short u16;
typedef unsigned int u32;
typedef __bf16 bf16_t;
typedef bf16_t bf16x8 __attribute__((ext_vector_type(8)));
typedef float f32x4 __attribute__((ext_vector_type(4)));

#define S_LEN 2048
#define DM 1024
#define NH 16
#define HDIM 64

// ---- helpers ----
__device__ __forceinline__ u16 f2b(float f) {
  u32 u = __builtin_bit_cast(u32, f);
  u32 r = (u + 0x7FFFu + ((u >> 16) & 1u)) >> 16;  // RNE
  return (u16)r;
}

__device__ __forceinline__ void gload16(const void* g, void* l) {
  __builtin_amdgcn_global_load_lds((const __attribute__((address_space(1))) void*)g,
                                   (__attribute__((address_space(3))) void*)l,
                                   16, 0, 0);
}

__device__ __forceinline__ bf16x8 ld_bf8(const u16* p) {
  return *reinterpret_cast<const bf16x8*>(p);
}

// ---- kernel 1: x f32 -> bf16 ----
__global__ __launch_bounds__(256) void k_cvt(const float* __restrict__ in, u16* __restrict__ out) {
  int i = (blockIdx.x * 256 + threadIdx.x) * 4;
  float4 v = *reinterpret_cast<const float4*>(in + i);
  ushort4 o = make_ushort4(f2b(v.x), f2b(v.y), f2b(v.z), f2b(v.w));
  *reinterpret_cast<ushort4*>(out + i) = o;
}

// ---- kernel 2: W [K][N] f32 -> Wt [N][K] bf16 ----
__global__ __launch_bounds__(256) void k_wt(const float* __restrict__ W, u16* __restrict__ Wt) {
  __shared__ float t[32][33];
  int n0 = blockIdx.x * 32, k0 = blockIdx.y * 32;
  int tx = threadIdx.x & 31, ty = threadIdx.x >> 5;
#pragma unroll
  for (int i = 0; i < 32; i += 8)
    t[ty + i][tx] = W[(size_t)(k0 + ty + i) * DM + n0 + tx];
  __syncthreads();
#pragma unroll
  for (int i = 0; i < 32; i += 8)
    Wt[(size_t)(n0 + ty + i) * DM + k0 + tx] = f2b(t[tx][ty + i]);
}

// ---- kernel 3: C = Xb[M][K] * W  (W given as Wt[N][K]); out bf16 in [B,H,S,HD] ----
__global__ __launch_bounds__(256) void k_gemm(const u16* __restrict__ Xb, const u16* __restrict__ Wt,
                                              u16* __restrict__ Out) {
  __shared__ u16 At[128 * 32];
  __shared__ u16 Bt[128 * 32];
  int tid = threadIdx.x;
  int lane = tid & 63, w = tid >> 6;
  int l15 = lane & 15, lg = lane >> 4;
  int wm = w >> 1, wn = w & 1;
  int n0 = blockIdx.x * 128, m0 = blockIdx.y * 128;
  f32x4 acc[4][4] = {};
  for (int kt = 0; kt < DM / 32; ++kt) {
    int kk = kt * 32;
#pragma unroll
    for (int i = 0; i < 2; ++i) {
      int t2 = i * 256 + tid;
      int row = t2 >> 2, c16 = t2 & 3;
      gload16(Xb + (size_t)(m0 + row) * DM + kk + c16 * 8, At + t2 * 8);
      gload16(Wt + (size_t)(n0 + row) * DM + kk + c16 * 8, Bt + t2 * 8);
    }
    __syncthreads();
    bf16x8 af[4], bfr[4];
#pragma unroll
    for (int mi = 0; mi < 4; ++mi)
      af[mi] = ld_bf8(At + (wm * 64 + mi * 16 + l15) * 32 + lg * 8);
#pragma unroll
    for (int ni = 0; ni < 4; ++ni)
      bfr[ni] = ld_bf8(Bt + (wn * 64 + ni * 16 + l15) * 32 + lg * 8);
#pragma unroll
    for (int mi = 0; mi < 4; ++mi)
#pragma unroll
      for (int ni = 0; ni < 4; ++ni)
        acc[mi][ni] = __builtin_amdgcn_mfma_f32_16x16x32_bf16(af[mi], bfr[ni], acc[mi][ni], 0, 0, 0);
    __syncthreads();
  }
#pragma unroll
  for (int mi = 0; mi < 4; ++mi) {
#pragma unroll
    for (int ni = 0; ni < 4; ++ni) {
#pragma unroll
      for (int r = 0; r < 4; ++r) {
        int m = m0 + wm * 64 + mi * 16 + lg * 4 + r;
        int n = n0 + wn * 64 + ni * 16 + l15;
        int b = m >> 11, s = m & 2047;
        int h = n >> 6, hd = n & 63;
        Out[(((size_t)(b * NH + h)) * S_LEN + s) * HDIM + hd] = f2b(acc[mi][ni][r]);
      }
    }
  }
}

// ---- kernel 4: V [bh][S][HD] -> Vt [bh][HD][S] (bf16) ----
__global__ __launch_bounds__(256) void k_vt(const u16* __restrict__ V, u16* __restrict__ Vt) {
  __shared__ u16 t[32][33];
  int hd0 = blockIdx.x * 32, s0 = blockIdx.y * 32;
  size_t base = (size_t)blockIdx.z * S_LEN * HDIM;
  int tx = threadIdx.x & 31, ty = threadIdx.x >> 5;
#pragma unroll
  for (int i = 0; i < 32; i += 8)
    t[ty + i][tx] = V[base + (size_t)(s0 + ty + i) * HDIM + hd0 + tx];
  __syncthreads();
#pragma unroll
  for (int i = 0; i < 32; i += 8)
    Vt[base + (size_t)(hd0 + ty + i) * S_LEN + s0 + tx] = t[tx][ty + i];
}

// ---- kernel 5: causal flash attention, 4 waves x 16 q-rows, K-tile = 64 ----
__global__ __launch_bounds__(256) void k_attn(const u16* __restrict__ Qb, const u16* __restrict__ Kb,
                                              const u16* __restrict__ Vtb, float* __restrict__ out) {
  __shared__ u16 Plds[4][16 * 72];  // per-wave P tile, 144B row stride (16B aligned)
  int tid = threadIdx.x, lane = tid & 63, w = tid >> 6;
  int l15 = lane & 15, lg = lane >> 4;
  int qb = blockIdx.x * 64, bh = blockIdx.y;
  int b = bh >> 4, h = bh & 15;
  const u16* Qp = Qb + (size_t)bh * S_LEN * HDIM;
  const u16* Kp = Kb + (size_t)bh * S_LEN * HDIM;
  const u16* Vp = Vtb + (size_t)bh * HDIM * S_LEN;
  int qrow = qb + w * 16;
  bf16x8 qf[2];
#pragma unroll
  for (int c = 0; c < 2; ++c)
    qf[c] = ld_bf8(Qp + (size_t)(qrow + l15) * HDIM + c * 32 + lg * 8);
  f32x4 o[4] = {};
  float mx[4], ls[4];
#pragma unroll
  for (int r = 0; r < 4; ++r) { mx[r] = -1e30f; ls[r] = 0.f; }
  int nt = qb / 64 + 1;
  u16* Pw = Plds[w];
  for (int kt = 0; kt < nt; ++kt) {
    int k0 = kt * 64;
    f32x4 sc[4] = {};
#pragma unroll
    for (int kb = 0; kb < 4; ++kb) {
#pragma unroll
      for (int c = 0; c < 2; ++c) {
        bf16x8 kf = ld_bf8(Kp + (size_t)(k0 + kb * 16 + l15) * HDIM + c * 32 + lg * 8);
        sc[kb] = __builtin_amdgcn_mfma_f32_16x16x32_bf16(qf[c], kf, sc[kb], 0, 0, 0);
      }
    }
    bool last = (kt == nt - 1);
    float pv[4][4];
    float pm[4] = {-1e30f, -1e30f, -1e30f, -1e30f};
#pragma unroll
    for (int kb = 0; kb < 4; ++kb) {
      int key = k0 + kb * 16 + l15;
#pragma unroll
      for (int r = 0; r < 4; ++r) {
        float s = sc[kb][r] * 0.125f;
        int row = qrow + lg * 4 + r;
        if (last && key > row) s = -1e30f;
        pv[kb][r] = s;
        pm[r] = fmaxf(pm[r], s);
      }
    }
#pragma unroll
    for (int r = 0; r < 4; ++r) {
#pragma unroll
      for (int d = 1; d < 16; d <<= 1)
        pm[r] = fmaxf(pm[r], __shfl_xor(pm[r], d));
    }
    float corr[4], rsum[4];
#pragma unroll
    for (int r = 0; r < 4; ++r) {
      float nm = fmaxf(mx[r], pm[r]);
      corr[r] = __expf(mx[r] - nm);
      mx[r] = nm;
      rsum[r] = 0.f;
    }
#pragma unroll
    for (int kb = 0; kb < 4; ++kb)
#pragma unroll
      for (int r = 0; r < 4; ++r) {
        float p = __expf(pv[kb][r] - mx[r]);
        pv[kb][r] = p;
        rsum[r] += p;
      }
#pragma unroll
    for (int r = 0; r < 4; ++r) {
#pragma unroll
      for (int d = 1; d < 16; d <<= 1)
        rsum[r] += __shfl_xor(rsum[r], d);
      ls[r] = ls[r] * corr[r] + rsum[r];
    }
#pragma unroll
    for (int n = 0; n < 4; ++n)
#pragma unroll
      for (int r = 0; r < 4; ++r)
        o[n][r] *= corr[r];
#pragma unroll
    for (int kb = 0; kb < 4; ++kb)
#pragma unroll
      for (int r = 0; r < 4; ++r)
        Pw[(lg * 4 + r) * 72 + kb * 16 + l15] = f2b(pv[kb][r]);
    __syncthreads();
    bf16x8 pf[2];
#pragma unroll
    for (int c = 0; c < 2; ++c)
      pf[c] = ld_bf8(Pw + l15 * 72 + c * 32 + lg * 8);
#pragma unroll
    for (int n = 0; n < 4; ++n) {
#pragma unroll
      for (int c = 0; c < 2; ++c) {
        bf16x8 vf = ld_bf8(Vp + (size_t)(n * 16 + l15) * S_LEN + k0 + c * 32 + lg * 8);
        o[n] = __builtin_amdgcn_mfma_f32_16x16x32_bf16(pf[c], vf, o[n], 0, 0, 0);
      }
    }
    __syncthreads();
  }
#pragma unroll
  for (int r = 0; r < 4; ++r) {
    float inv = 1.f / ls[r];
    int row = qrow + lg * 4 + r;
#pragma unroll
    for (int n = 0; n < 4; ++n)
      out[((size_t)b * S_LEN + row) * DM + h * HDIM + n * 16 + l15] = o[n][r] * inv;
  }
}

extern "C" void kernel_launch(void* const* d_in, const int* in_sizes, int n_in,
                              void* d_out, int out_size, void* d_ws, size_t ws_size,
                              hipStream_t stream) {
  const float* x  = (const float*)d_in[0];
  const float* Wq = (const float*)d_in[1];
  const float* Wk = (const float*)d_in[2];
  const float* Wv = (const float*)d_in[3];
  float* out = (float*)d_out;

  // workspace layout (u16 elements); total ~90 MB
  u16* ws  = (u16*)d_ws;
  u16* xb  = ws;                    // 8192*1024
  u16* wqt = xb + 8388608;          // 1024*1024
  u16* wkt = wqt + 1048576;
  u16* wvt = wkt + 1048576;
  u16* Qb  = wvt + 1048576;         // 8192*1024 each, [B,H,S,HD]
  u16* Kb  = Qb + 8388608;
  u16* Vb  = Kb + 8388608;
  u16* Vtb = Vb + 8388608;          // [B,H,HD,S]

  k_cvt<<<8192, 256, 0, stream>>>(x, xb);
  k_wt<<<dim3(32, 32), 256, 0, stream>>>(Wq, wqt);
  k_wt<<<dim3(32, 32), 256, 0, stream>>>(Wk, wkt);
  k_wt<<<dim3(32, 32), 256, 0, stream>>>(Wv, wvt);
  k_gemm<<<dim3(8, 64), 256, 0, stream>>>(xb, wqt, Qb);
  k_gemm<<<dim3(8, 64), 256, 0, stream>>>(xb, wkt, Kb);
  k_gemm<<<dim3(8, 64), 256, 0, stream>>>(xb, wvt, Vb);
  k_vt<<<dim3(2, 64, 64), 256, 0, stream>>>(Vb, Vtb);
  k_attn<<<dim3(32, 64), 256, 0, stream>>>(Qb, Kb, Vtb, out);
}

// Round 2
// 352.773 us; speedup vs baseline: 1.9286x; 1.9286x over previous
//
#include <hip/hip_runtime.h>

typedef unsigned short u16;
typedef unsigned int u32;
typedef __bf16 bf16_t;
typedef bf16_t bf16x8 __attribute__((ext_vector_type(8)));
typedef float f32x4 __attribute__((ext_vector_type(4)));

#define S_LEN 2048
#define DM 1024
#define NH 16
#define HDIM 64
#define PSTR 80  // P-tile LDS row stride in u16 (160B: lg banks 0/8/16/24, no 4-way)

// ---- helpers ----
__device__ __forceinline__ u16 f2b(float f) {
  u32 u = __builtin_bit_cast(u32, f);
  u32 r = (u + 0x7FFFu + ((u >> 16) & 1u)) >> 16;  // RNE
  return (u16)r;
}

__device__ __forceinline__ void gload16(const void* g, void* l) {
  __builtin_amdgcn_global_load_lds((const __attribute__((address_space(1))) void*)g,
                                   (__attribute__((address_space(3))) void*)l,
                                   16, 0, 0);
}

__device__ __forceinline__ bf16x8 ld_bf8(const u16* p) {
  return *reinterpret_cast<const bf16x8*>(p);
}

// ---- kernel 1: x f32 -> bf16 ----
__global__ __launch_bounds__(256) void k_cvt(const float* __restrict__ in, u16* __restrict__ out) {
  int i = (blockIdx.x * 256 + threadIdx.x) * 4;
  float4 v = *reinterpret_cast<const float4*>(in + i);
  ushort4 o = make_ushort4(f2b(v.x), f2b(v.y), f2b(v.z), f2b(v.w));
  *reinterpret_cast<ushort4*>(out + i) = o;
}

// ---- kernel 2: W [K][N] f32 -> Wt [N][K] bf16 ----
__global__ __launch_bounds__(256) void k_wt(const float* __restrict__ W, u16* __restrict__ Wt) {
  __shared__ float t[32][33];
  int n0 = blockIdx.x * 32, k0 = blockIdx.y * 32;
  int tx = threadIdx.x & 31, ty = threadIdx.x >> 5;
#pragma unroll
  for (int i = 0; i < 32; i += 8)
    t[ty + i][tx] = W[(size_t)(k0 + ty + i) * DM + n0 + tx];
  __syncthreads();
#pragma unroll
  for (int i = 0; i < 32; i += 8)
    Wt[(size_t)(n0 + ty + i) * DM + k0 + tx] = f2b(t[tx][ty + i]);
}

// ---- kernel 3: C = Xb[M][K] * W  (W given as Wt[N][K]); out bf16 in [B,H,S,HD], scaled ----
__global__ __launch_bounds__(256) void k_gemm(const u16* __restrict__ Xb, const u16* __restrict__ Wt,
                                              u16* __restrict__ Out, float scale) {
  __shared__ u16 At[128 * 32];
  __shared__ u16 Bt[128 * 32];
  int tid = threadIdx.x;
  int lane = tid & 63, w = tid >> 6;
  int l15 = lane & 15, lg = lane >> 4;
  int wm = w >> 1, wn = w & 1;
  int n0 = blockIdx.x * 128, m0 = blockIdx.y * 128;
  f32x4 acc[4][4] = {};
  for (int kt = 0; kt < DM / 32; ++kt) {
    int kk = kt * 32;
#pragma unroll
    for (int i = 0; i < 2; ++i) {
      int t2 = i * 256 + tid;
      int row = t2 >> 2, c16 = t2 & 3;
      gload16(Xb + (size_t)(m0 + row) * DM + kk + c16 * 8, At + t2 * 8);
      gload16(Wt + (size_t)(n0 + row) * DM + kk + c16 * 8, Bt + t2 * 8);
    }
    __syncthreads();
    bf16x8 af[4], bfr[4];
#pragma unroll
    for (int mi = 0; mi < 4; ++mi)
      af[mi] = ld_bf8(At + (wm * 64 + mi * 16 + l15) * 32 + lg * 8);
#pragma unroll
    for (int ni = 0; ni < 4; ++ni)
      bfr[ni] = ld_bf8(Bt + (wn * 64 + ni * 16 + l15) * 32 + lg * 8);
#pragma unroll
    for (int mi = 0; mi < 4; ++mi)
#pragma unroll
      for (int ni = 0; ni < 4; ++ni)
        acc[mi][ni] = __builtin_amdgcn_mfma_f32_16x16x32_bf16(af[mi], bfr[ni], acc[mi][ni], 0, 0, 0);
    __syncthreads();
  }
#pragma unroll
  for (int mi = 0; mi < 4; ++mi) {
#pragma unroll
    for (int ni = 0; ni < 4; ++ni) {
#pragma unroll
      for (int r = 0; r < 4; ++r) {
        int m = m0 + wm * 64 + mi * 16 + lg * 4 + r;
        int n = n0 + wn * 64 + ni * 16 + l15;
        int b = m >> 11, s = m & 2047;
        int h = n >> 6, hd = n & 63;
        Out[(((size_t)(b * NH + h)) * S_LEN + s) * HDIM + hd] = f2b(acc[mi][ni][r] * scale);
      }
    }
  }
}

// ---- kernel 4: V [bh][S][HD] -> Vt [bh][HD][S] (bf16) ----
__global__ __launch_bounds__(256) void k_vt(const u16* __restrict__ V, u16* __restrict__ Vt) {
  __shared__ u16 t[32][33];
  int hd0 = blockIdx.x * 32, s0 = blockIdx.y * 32;
  size_t base = (size_t)blockIdx.z * S_LEN * HDIM;
  int tx = threadIdx.x & 31, ty = threadIdx.x >> 5;
#pragma unroll
  for (int i = 0; i < 32; i += 8)
    t[ty + i][tx] = V[base + (size_t)(s0 + ty + i) * HDIM + hd0 + tx];
  __syncthreads();
#pragma unroll
  for (int i = 0; i < 32; i += 8)
    Vt[base + (size_t)(hd0 + ty + i) * S_LEN + s0 + tx] = t[tx][ty + i];
}

// ---- per-wave flash-attention over one 16-row q strip ----
// Scores arrive pre-scaled by 1/8*log2(e) (folded into Q projection); exp2 softmax.
__device__ __forceinline__ void attn_strip(const u16* __restrict__ Qp, const u16* __restrict__ Kp,
                                           const u16* __restrict__ Vp, float* __restrict__ out,
                                           int b, int h, int qrow, int nt, int lane,
                                           u16* __restrict__ Pw) {
  int l15 = lane & 15, lg = lane >> 4;
  bf16x8 qf0 = ld_bf8(Qp + (size_t)(qrow + l15) * HDIM + lg * 8);
  bf16x8 qf1 = ld_bf8(Qp + (size_t)(qrow + l15) * HDIM + 32 + lg * 8);
  f32x4 o[4] = {};
  float mx[4], ls[4];
#pragma unroll
  for (int r = 0; r < 4; ++r) { mx[r] = -1e30f; ls[r] = 0.f; }
  for (int kt = 0; kt < nt; ++kt) {
    int k0 = kt * 64;
    // V loads first: independent, consumed only after softmax (latency hidden)
    bf16x8 vf[4][2];
#pragma unroll
    for (int n = 0; n < 4; ++n)
#pragma unroll
      for (int c = 0; c < 2; ++c)
        vf[n][c] = ld_bf8(Vp + (size_t)(n * 16 + l15) * S_LEN + k0 + c * 32 + lg * 8);
    f32x4 sc[4] = {};
#pragma unroll
    for (int kb = 0; kb < 4; ++kb) {
      bf16x8 kf0 = ld_bf8(Kp + (size_t)(k0 + kb * 16 + l15) * HDIM + lg * 8);
      bf16x8 kf1 = ld_bf8(Kp + (size_t)(k0 + kb * 16 + l15) * HDIM + 32 + lg * 8);
      sc[kb] = __builtin_amdgcn_mfma_f32_16x16x32_bf16(qf0, kf0, sc[kb], 0, 0, 0);
      sc[kb] = __builtin_amdgcn_mfma_f32_16x16x32_bf16(qf1, kf1, sc[kb], 0, 0, 0);
    }
    float p[4][4];
    float pm[4] = {-1e30f, -1e30f, -1e30f, -1e30f};
    if (kt == nt - 1) {  // diagonal tile: causal mask (wave-uniform branch)
#pragma unroll
      for (int kb = 0; kb < 4; ++kb) {
        int key = k0 + kb * 16 + l15;
#pragma unroll
        for (int r = 0; r < 4; ++r) {
          int row = qrow + lg * 4 + r;
          float s = (key > row) ? -1e30f : sc[kb][r];
          p[kb][r] = s;
          pm[r] = fmaxf(pm[r], s);
        }
      }
    } else {
#pragma unroll
      for (int kb = 0; kb < 4; ++kb)
#pragma unroll
        for (int r = 0; r < 4; ++r) {
          p[kb][r] = sc[kb][r];
          pm[r] = fmaxf(pm[r], sc[kb][r]);
        }
    }
#pragma unroll
    for (int r = 0; r < 4; ++r)
#pragma unroll
      for (int d = 1; d < 16; d <<= 1)
        pm[r] = fmaxf(pm[r], __shfl_xor(pm[r], d));
    float corr[4], rsum[4];
#pragma unroll
    for (int r = 0; r < 4; ++r) {
      float nm = fmaxf(mx[r], pm[r]);
      corr[r] = __builtin_amdgcn_exp2f(mx[r] - nm);
      mx[r] = nm;
      rsum[r] = 0.f;
    }
#pragma unroll
    for (int kb = 0; kb < 4; ++kb)
#pragma unroll
      for (int r = 0; r < 4; ++r) {
        float e = __builtin_amdgcn_exp2f(p[kb][r] - mx[r]);
        p[kb][r] = e;
        rsum[r] += e;
      }
#pragma unroll
    for (int r = 0; r < 4; ++r) {
#pragma unroll
      for (int d = 1; d < 16; d <<= 1)
        rsum[r] += __shfl_xor(rsum[r], d);
      ls[r] = ls[r] * corr[r] + rsum[r];
    }
#pragma unroll
    for (int n = 0; n < 4; ++n)
#pragma unroll
      for (int r = 0; r < 4; ++r)
        o[n][r] *= corr[r];
    // P (C-layout) -> LDS -> A-layout fragments; per-wave buffer, no barrier needed
#pragma unroll
    for (int kb = 0; kb < 4; ++kb)
#pragma unroll
      for (int r = 0; r < 4; ++r)
        Pw[(lg * 4 + r) * PSTR + kb * 16 + l15] = f2b(p[kb][r]);
    asm volatile("" ::: "memory");  // keep write->read order; DS is in-order per wave
    bf16x8 pf0 = ld_bf8(Pw + l15 * PSTR + lg * 8);
    bf16x8 pf1 = ld_bf8(Pw + l15 * PSTR + 32 + lg * 8);
#pragma unroll
    for (int n = 0; n < 4; ++n) {
      o[n] = __builtin_amdgcn_mfma_f32_16x16x32_bf16(pf0, vf[n][0], o[n], 0, 0, 0);
      o[n] = __builtin_amdgcn_mfma_f32_16x16x32_bf16(pf1, vf[n][1], o[n], 0, 0, 0);
    }
  }
#pragma unroll
  for (int r = 0; r < 4; ++r) {
    float inv = 1.f / ls[r];
    int row = qrow + lg * 4 + r;
#pragma unroll
    for (int n = 0; n < 4; ++n)
      out[((size_t)b * S_LEN + row) * DM + h * HDIM + n * 16 + l15] = o[n][r] * inv;
  }
}

// ---- kernel 5: causal flash attention ----
// Grid 1024 (flattened). Swizzle: XCD j%8 owns 8 heads, walks them one at a time.
// Block handles q-tiles x and 31-x (uniform 33 K-tiles -> balanced). Waves independent.
__global__ __launch_bounds__(256, 4) void k_attn(const u16* __restrict__ Qb, const u16* __restrict__ Kb,
                                                 const u16* __restrict__ Vtb, float* __restrict__ out) {
  __shared__ u16 Plds[4][16 * PSTR];
  int j = blockIdx.x;
  int m = j >> 3;
  int x = m & 15;                    // q-tile pair index
  int bh = (j & 7) + 8 * (m >> 4);   // head: same-XCD blocks share heads
  int tid = threadIdx.x, lane = tid & 63, w = tid >> 6;
  int b = bh >> 4, h = bh & 15;
  const u16* Qp = Qb + (size_t)bh * S_LEN * HDIM;
  const u16* Kp = Kb + (size_t)bh * S_LEN * HDIM;
  const u16* Vp = Vtb + (size_t)bh * HDIM * S_LEN;
  u16* Pw = Plds[w];
  attn_strip(Qp, Kp, Vp, out, b, h, x * 64 + w * 16, x + 1, lane, Pw);
  attn_strip(Qp, Kp, Vp, out, b, h, (31 - x) * 64 + w * 16, 32 - x, lane, Pw);
}

extern "C" void kernel_launch(void* const* d_in, const int* in_sizes, int n_in,
                              void* d_out, int out_size, void* d_ws, size_t ws_size,
                              hipStream_t stream) {
  const float* x  = (const float*)d_in[0];
  const float* Wq = (const float*)d_in[1];
  const float* Wk = (const float*)d_in[2];
  const float* Wv = (const float*)d_in[3];
  float* out = (float*)d_out;

  // workspace layout (u16 elements); total ~90 MB
  u16* ws  = (u16*)d_ws;
  u16* xb  = ws;                    // 8192*1024
  u16* wqt = xb + 8388608;          // 1024*1024
  u16* wkt = wqt + 1048576;
  u16* wvt = wkt + 1048576;
  u16* Qb  = wvt + 1048576;         // 8192*1024 each, [B,H,S,HD]
  u16* Kb  = Qb + 8388608;
  u16* Vb  = Kb + 8388608;
  u16* Vtb = Vb + 8388608;          // [B,H,HD,S]

  const float qscale = 0.125f * 1.44269504088896f;  // 1/sqrt(64) * log2(e)

  k_cvt<<<8192, 256, 0, stream>>>(x, xb);
  k_wt<<<dim3(32, 32), 256, 0, stream>>>(Wq, wqt);
  k_wt<<<dim3(32, 32), 256, 0, stream>>>(Wk, wkt);
  k_wt<<<dim3(32, 32), 256, 0, stream>>>(Wv, wvt);
  k_gemm<<<dim3(8, 64), 256, 0, stream>>>(xb, wqt, Qb, qscale);
  k_gemm<<<dim3(8, 64), 256, 0, stream>>>(xb, wkt, Kb, 1.0f);
  k_gemm<<<dim3(8, 64), 256, 0, stream>>>(xb, wvt, Vb, 1.0f);
  k_vt<<<dim3(2, 64, 64), 256, 0, stream>>>(Vb, Vtb);
  k_attn<<<1024, 256, 0, stream>>>(Qb, Kb, Vtb, out);
}